// Round 6
// baseline (298.687 us; speedup 1.0000x reference)
//
#include <hip/hip_runtime.h>
#include <hip/hip_bf16.h>

#define B_ 4
#define C_ 128
#define N_ 8192
#define K_ 16
#define NBLOCKS 1024

typedef __attribute__((ext_vector_type(8))) short short8;
typedef __attribute__((ext_vector_type(4))) float floatx4;

static __device__ __forceinline__ unsigned short f2b(float x) {
  return __builtin_bit_cast(unsigned short, __float2bfloat16(x));
}
static __device__ __forceinline__ void unpack8(uint4 u, float* f) {
  const unsigned* w = (const unsigned*)&u;
#pragma unroll
  for (int i = 0; i < 4; i++) {
    f[2 * i]     = __builtin_bit_cast(float, w[i] << 16);
    f[2 * i + 1] = __builtin_bit_cast(float, w[i] & 0xffff0000u);
  }
}

// workspace byte offsets
#define OFF_LOCAL 0ULL
#define OFF_EDGE  8388608ULL
#define OFF_WBF1  16777216ULL
#define OFF_WBF2  16809984ULL
#define OFF_ACC   16842752ULL   // 512 floats (BN sums)
#define OFF_BAR   16844800ULL   // 2 ints (grid barrier)
#define WS_BYTES  16844808ULL

// Init: cast W -> bf16; zero accumulators + barrier counters.
__global__ __launch_bounds__(256) void k_init(const float* __restrict__ w1,
    const float* __restrict__ w2, unsigned short* __restrict__ wbf1,
    unsigned short* __restrict__ wbf2, float* __restrict__ acc, int* __restrict__ bar) {
  int i = blockIdx.x * 256 + threadIdx.x;
  wbf1[i] = f2b(w1[i]);
  wbf2[i] = f2b(w2[i]);
  if (blockIdx.x == 0) {
    acc[threadIdx.x] = 0.f;
    acc[threadIdx.x + 256] = 0.f;
    if (threadIdx.x < 2) bar[threadIdx.x] = 0;
  }
}

// XCD-affine: batch b on XCDs {2b,2b+1}; chunk in [0,256).
static __device__ __forceinline__ void swz(int bid, int& b, int& chunk) {
  b = (bid & 7) >> 1;
  chunk = ((bid >> 3) << 1) | (bid & 1);
}

// Grid barrier. RELEASE arrive -> buffer_wbl2 (writeback, lines stay resident).
// RELAXED spin -> no L2 invalidate. Correct regardless of block->XCD mapping.
static __device__ __forceinline__ void gridbar(int* bar, int tid) {
  __syncthreads();
  if (tid == 0) {
    __hip_atomic_fetch_add(bar, 1, __ATOMIC_RELEASE, __HIP_MEMORY_SCOPE_AGENT);
    while (__hip_atomic_load(bar, __ATOMIC_RELAXED, __HIP_MEMORY_SCOPE_AGENT) < NBLOCKS)
      __builtin_amdgcn_s_sleep(2);
  }
  __syncthreads();
}

// Fused: GEMM -> bar -> stats -> bar -> coef -> out. 1024 blocks x 32 n, all co-resident.
__global__ __launch_bounds__(256, 4) void k_fused(const float* __restrict__ feat,
    const int* __restrict__ knn, const unsigned short* __restrict__ wbf1,
    const unsigned short* __restrict__ wbf2, const float* __restrict__ gamma,
    const float* __restrict__ beta, unsigned short* __restrict__ localB,
    unsigned short* __restrict__ edgeB, float* __restrict__ acc, int* __restrict__ bar,
    float* __restrict__ out) {
  __shared__ __align__(16) unsigned short lds_u[8704];  // GEMM stage [c][36] + 2x out [32][136]
  __shared__ int knn_s[512];
  __shared__ float red[512];
  __shared__ float ca[256], cb[256];
  const int t = threadIdx.x;
  int b, chunk; swz(blockIdx.x, b, chunk);
  const int n0 = chunk << 5;

  // ---- Phase 1: dual GEMM (verified R5 body) ----
  {
    const float* fb = feat + (size_t)b * C_ * N_;
#pragma unroll
    for (int i = 0; i < 4; i++) {
      int c = i * 32 + (t >> 3);
      int n4 = (t & 7) << 2;
      floatx4 f = __builtin_nontemporal_load((const floatx4*)&fb[(size_t)c * N_ + n0 + n4]);
      ushort4 u = make_ushort4(f2b(f[0]), f2b(f[1]), f2b(f[2]), f2b(f[3]));
      *(ushort4*)&lds_u[c * 36 + n4] = u;
    }
    __syncthreads();
    const int lane = t & 63, wv = t >> 6, l15 = lane & 15, q = lane >> 4;
    const int gw = wv >> 1, nt = wv & 1;
    short8 bfrag[4];
#pragma unroll
    for (int ks = 0; ks < 4; ks++)
#pragma unroll
      for (int j = 0; j < 8; j++)
        bfrag[ks][j] = (short)lds_u[(ks * 32 + q * 8 + j) * 36 + nt * 16 + l15];
    __syncthreads();
    const unsigned short* Wg = gw ? wbf2 : wbf1;
    floatx4 gacc[8];
#pragma unroll
    for (int mt = 0; mt < 8; mt++) gacc[mt] = (floatx4){0.f, 0.f, 0.f, 0.f};
#pragma unroll
    for (int ks = 0; ks < 4; ks++) {
      short8 af[8];
#pragma unroll
      for (int mt = 0; mt < 8; mt++)
        af[mt] = *(const short8*)(Wg + (size_t)(mt * 16 + l15) * 128 + ks * 32 + q * 8);
#pragma unroll
      for (int mt = 0; mt < 8; mt++)
        gacc[mt] = __builtin_amdgcn_mfma_f32_16x16x32_bf16(af[mt], bfrag[ks], gacc[mt], 0, 0, 0);
    }
    unsigned short* ot = lds_u + gw * 4352;
#pragma unroll
    for (int mt = 0; mt < 8; mt++) {
      ushort4 u = make_ushort4(f2b(gacc[mt][0]), f2b(gacc[mt][1]), f2b(gacc[mt][2]), f2b(gacc[mt][3]));
      *(ushort4*)&ot[(nt * 16 + l15) * 136 + mt * 16 + q * 4] = u;
    }
    __syncthreads();
#pragma unroll
    for (int g = 0; g < 2; g++) {
      unsigned short* dst = (g ? edgeB : localB) + ((size_t)b * N_ + n0) * 128;
#pragma unroll
      for (int i = 0; i < 2; i++) {
        int ng = i * 16 + (t >> 4);
        int o8 = (t & 15) * 8;
        float4 v = *(float4*)&lds_u[g * 4352 + ng * 136 + o8];
        *(float4*)&dst[(size_t)ng * 128 + o8] = v;
      }
    }
  }
  // prep for stats while stores drain
  red[t] = 0.f; red[t + 256] = 0.f;
  {
    const int* kb = knn + ((size_t)b * N_ + n0) * K_;
    knn_s[t] = kb[t];
    knn_s[t + 256] = kb[t + 256];
  }
  gridbar(bar + 0, t);   // edge/local now visible; L2 stays warm (wbl2, no inv)

  // ---- Phase 2: BN stats ----
  const int slot = t >> 4, co = t & 15;
  const unsigned short* lb = localB + (size_t)b * N_ * 128;
  const unsigned short* eb = edgeB + (size_t)b * N_ * 128;
  {
    float lS[8] = {0,0,0,0,0,0,0,0}, lQ[8] = {0,0,0,0,0,0,0,0};
    float dS[8] = {0,0,0,0,0,0,0,0}, dQ[8] = {0,0,0,0,0,0,0,0};
#pragma unroll
    for (int h = 0; h < 2; h++) {
      int nl = slot + h * 16;
      uint4 lu = *(const uint4*)&lb[(size_t)(n0 + nl) * 128 + co * 8];
      float l[8]; unpack8(lu, l);
      float se[8] = {0,0,0,0,0,0,0,0}, se2[8] = {0,0,0,0,0,0,0,0};
#pragma unroll
      for (int r = 0; r < 2; r++) {
        uint4 eu[8];
#pragma unroll
        for (int k = 0; k < 8; k++)
          eu[k] = *(const uint4*)&eb[(size_t)knn_s[nl * 16 + r * 8 + k] * 128 + co * 8];
#pragma unroll
        for (int k = 0; k < 8; k++) {
          float e[8]; unpack8(eu[k], e);
#pragma unroll
          for (int j = 0; j < 8; j++) { se[j] += e[j]; se2[j] = fmaf(e[j], e[j], se2[j]); }
        }
      }
#pragma unroll
      for (int j = 0; j < 8; j++) {
        lS[j] += l[j];
        lQ[j] = fmaf(l[j], l[j], lQ[j]);
        dS[j] += se[j] - 16.f * l[j];
        dQ[j] += fmaf(-2.f * l[j], se[j], se2[j]) + 16.f * l[j] * l[j];
      }
    }
#pragma unroll
    for (int off = 16; off <= 32; off <<= 1) {
#pragma unroll
      for (int j = 0; j < 8; j++) {
        lS[j] += __shfl_xor(lS[j], off);
        lQ[j] += __shfl_xor(lQ[j], off);
        dS[j] += __shfl_xor(dS[j], off);
        dQ[j] += __shfl_xor(dQ[j], off);
      }
    }
    if ((t & 48) == 0) {
      int ch = co * 8;
#pragma unroll
      for (int j = 0; j < 8; j++) {
        atomicAdd(&red[ch + j], lS[j]);
        atomicAdd(&red[128 + ch + j], dS[j]);
        atomicAdd(&red[256 + ch + j], lQ[j]);
        atomicAdd(&red[384 + ch + j], dQ[j]);
      }
    }
  }
  __syncthreads();
  if (t < 256) {
    atomicAdd(&acc[t], red[t]);
    atomicAdd(&acc[t + 256], red[t + 256]);
  }
  gridbar(bar + 1, t);

  // ---- Phase 3: per-block coef ----
  {
    float s = __hip_atomic_load(&acc[t], __ATOMIC_RELAXED, __HIP_MEMORY_SCOPE_AGENT);
    float q = __hip_atomic_load(&acc[t + 256], __ATOMIC_RELAXED, __HIP_MEMORY_SCOPE_AGENT);
    float cnt = (t < 128) ? 32768.f : 524288.f;
    float mean = s / cnt;
    float var = fmaxf(q / cnt - mean * mean, 0.f);
    float a = gamma[t] * rsqrtf(var + 1e-5f);
    ca[t] = a;
    cb[t] = beta[t] - mean * a;
  }
  __syncthreads();

  // ---- Phase 4: output (gathers hit warm L2; scattered stores coalesce in L2) ----
  {
    float* ob = out + (size_t)b * 256 * N_ + n0;
    float caE[8], cbE[8], caL[8], cbL[8];
#pragma unroll
    for (int j = 0; j < 8; j++) {
      caL[j] = ca[co * 8 + j];      cbL[j] = cb[co * 8 + j];
      caE[j] = ca[128 + co * 8 + j]; cbE[j] = cb[128 + co * 8 + j];
    }
#pragma unroll
    for (int h = 0; h < 2; h++) {
      int nl = slot + h * 16;
      uint4 lu = *(const uint4*)&lb[(size_t)(n0 + nl) * 128 + co * 8];
      float l[8]; unpack8(lu, l);
      float hc[8], av[8] = {0,0,0,0,0,0,0,0};
#pragma unroll
      for (int j = 0; j < 8; j++) hc[j] = fmaf(-l[j], caE[j], cbE[j]);
#pragma unroll
      for (int r = 0; r < 2; r++) {
        uint4 eu[8];
#pragma unroll
        for (int k = 0; k < 8; k++)
          eu[k] = *(const uint4*)&eb[(size_t)knn_s[nl * 16 + r * 8 + k] * 128 + co * 8];
#pragma unroll
        for (int k = 0; k < 8; k++) {
          float e[8]; unpack8(eu[k], e);
#pragma unroll
          for (int j = 0; j < 8; j++)
            av[j] += fmaxf(fmaf(e[j], caE[j], hc[j]), 0.f);
        }
      }
#pragma unroll
      for (int j = 0; j < 8; j++) {
        size_t c = (size_t)(co * 8 + j);
        ob[c * N_ + nl] = fmaxf(fmaf(l[j], caL[j], cbL[j]), 0.f);
        ob[(c + 128) * N_ + nl] = av[j] * 0.0625f;
      }
    }
  }
}

extern "C" void kernel_launch(void* const* d_in, const int* in_sizes, int n_in,
                              void* d_out, int out_size, void* d_ws, size_t ws_size,
                              hipStream_t stream) {
  const float* feat  = (const float*)d_in[0];
  const int*   knn   = (const int*)d_in[1];
  const float* w1    = (const float*)d_in[2];
  const float* w2    = (const float*)d_in[3];
  const float* gamma = (const float*)d_in[4];
  const float* beta  = (const float*)d_in[5];
  if (ws_size < WS_BYTES) return;
  unsigned char* ws = (unsigned char*)d_ws;
  unsigned short* localB = (unsigned short*)(ws + OFF_LOCAL);
  unsigned short* edgeB  = (unsigned short*)(ws + OFF_EDGE);
  unsigned short* wbf1   = (unsigned short*)(ws + OFF_WBF1);
  unsigned short* wbf2   = (unsigned short*)(ws + OFF_WBF2);
  float* acc             = (float*)(ws + OFF_ACC);
  int*   bar             = (int*)(ws + OFF_BAR);
  float* outp = (float*)d_out;

  hipLaunchKernelGGL(k_init, dim3(64), dim3(256), 0, stream, w1, w2, wbf1, wbf2, acc, bar);
  hipLaunchKernelGGL(k_fused, dim3(NBLOCKS), dim3(256), 0, stream,
                     feat, knn, wbf1, wbf2, gamma, beta, localB, edgeB, acc, bar, outp);
}

// Round 7
// 190.553 us; speedup vs baseline: 1.5675x; 1.5675x over previous
//
#include <hip/hip_runtime.h>
#include <hip/hip_bf16.h>

#define B_ 4
#define C_ 128
#define N_ 8192
#define K_ 16
#define NBLK_STATS 2048

typedef __attribute__((ext_vector_type(8))) short short8;
typedef __attribute__((ext_vector_type(4))) float floatx4;

static __device__ __forceinline__ unsigned short f2b(float x) {
  return __builtin_bit_cast(unsigned short, __float2bfloat16(x));
}
static __device__ __forceinline__ void unpack8(uint4 u, float* f) {
  const unsigned* w = (const unsigned*)&u;
#pragma unroll
  for (int i = 0; i < 4; i++) {
    f[2 * i]     = __builtin_bit_cast(float, w[i] << 16);
    f[2 * i + 1] = __builtin_bit_cast(float, w[i] & 0xffff0000u);
  }
}

// workspace byte offsets
#define OFF_LOCAL 0ULL
#define OFF_EDGE  8388608ULL
#define OFF_WBF1  16777216ULL
#define OFF_WBF2  16809984ULL
#define OFF_PART  16842752ULL         // 2048 * 512 floats
#define OFF_COEF  21037056ULL
#define OFF_Q     21039104ULL         // 12 ints: 3 kernels x 4 batch-queues
#define WS_BYTES  21039152ULL

// Claim a (batch, chunk) with batch matched to this block's PHYSICAL XCD pair.
// HW_REG_XCC_ID: getreg imm = id20 | offset0<<6 | (size4-1)<<11 = 6164 (m09-verified).
// Correct for ANY dispatch mapping: 4*cap chunks, 4*cap blocks, atomic claims with
// fallback scan => bijection. Garbage XCC read only hurts locality, never correctness.
static __device__ __forceinline__ void claim_chunk(int* q, int cap, int& b, int& chunk) {
  int xcd = __builtin_amdgcn_s_getreg(6164) & 7;
  int p = (xcd >> 1) & 3;
  int idx = atomicAdd(&q[p], 1);
  if (idx >= cap) {
#pragma unroll
    for (int s = 1; s < 4; s++) {
      int pp = (p + s) & 3;
      idx = atomicAdd(&q[pp], 1);
      if (idx < cap) { p = pp; break; }
    }
  }
  b = p;
  chunk = idx & (cap - 1);
}

// K0: cast W -> bf16; zero the claim queues.
__global__ __launch_bounds__(256) void k_init(const float* __restrict__ w1,
    const float* __restrict__ w2, unsigned short* __restrict__ wbf1,
    unsigned short* __restrict__ wbf2, int* __restrict__ q) {
  int i = blockIdx.x * 256 + threadIdx.x;
  wbf1[i] = f2b(w1[i]);
  wbf2[i] = f2b(w2[i]);
  if (blockIdx.x == 0 && threadIdx.x < 12) q[threadIdx.x] = 0;
}

// K1: MFMA dual-GEMM, (b,n,o) bf16 out. 1024 blocks x 32 n, XCD-affine claimed.
// Waves 0-1: W1->local, waves 2-3: W2->edge.
__global__ __launch_bounds__(256, 4) void k_gemm(const float* __restrict__ feat,
    const unsigned short* __restrict__ wbf1, const unsigned short* __restrict__ wbf2,
    unsigned short* __restrict__ localB, unsigned short* __restrict__ edgeB,
    int* __restrict__ q) {
  __shared__ __align__(16) unsigned short lds_u[8704];
  __shared__ int sbc[2];
  const int t = threadIdx.x;
  if (t == 0) { int b_, c_; claim_chunk(q, 256, b_, c_); sbc[0] = b_; sbc[1] = c_; }
  __syncthreads();
  const int b = sbc[0];
  const int n0 = sbc[1] << 5;
  const float* fb = feat + (size_t)b * C_ * N_;
#pragma unroll
  for (int i = 0; i < 4; i++) {
    int c = i * 32 + (t >> 3);
    int n4 = (t & 7) << 2;
    floatx4 f = __builtin_nontemporal_load((const floatx4*)&fb[(size_t)c * N_ + n0 + n4]);
    ushort4 u = make_ushort4(f2b(f[0]), f2b(f[1]), f2b(f[2]), f2b(f[3]));
    *(ushort4*)&lds_u[c * 36 + n4] = u;
  }
  __syncthreads();
  const int lane = t & 63, wv = t >> 6, l15 = lane & 15, qd = lane >> 4;
  const int gw = wv >> 1, nt = wv & 1;
  short8 bfrag[4];
#pragma unroll
  for (int ks = 0; ks < 4; ks++)
#pragma unroll
    for (int j = 0; j < 8; j++)
      bfrag[ks][j] = (short)lds_u[(ks * 32 + qd * 8 + j) * 36 + nt * 16 + l15];
  __syncthreads();
  const unsigned short* Wg = gw ? wbf2 : wbf1;
  floatx4 acc[8];
#pragma unroll
  for (int mt = 0; mt < 8; mt++) acc[mt] = (floatx4){0.f, 0.f, 0.f, 0.f};
#pragma unroll
  for (int ks = 0; ks < 4; ks++) {
    short8 af[8];
#pragma unroll
    for (int mt = 0; mt < 8; mt++)
      af[mt] = *(const short8*)(Wg + (size_t)(mt * 16 + l15) * 128 + ks * 32 + qd * 8);
#pragma unroll
    for (int mt = 0; mt < 8; mt++)
      acc[mt] = __builtin_amdgcn_mfma_f32_16x16x32_bf16(af[mt], bfrag[ks], acc[mt], 0, 0, 0);
  }
  unsigned short* ot = lds_u + gw * 4352;
#pragma unroll
  for (int mt = 0; mt < 8; mt++) {
    ushort4 u = make_ushort4(f2b(acc[mt][0]), f2b(acc[mt][1]), f2b(acc[mt][2]), f2b(acc[mt][3]));
    *(ushort4*)&ot[(nt * 16 + l15) * 136 + mt * 16 + qd * 4] = u;
  }
  __syncthreads();
#pragma unroll
  for (int g = 0; g < 2; g++) {
    unsigned short* dst = (g ? edgeB : localB) + ((size_t)b * N_ + n0) * 128;
#pragma unroll
    for (int i = 0; i < 2; i++) {
      int ng = i * 16 + (t >> 4);
      int o8 = (t & 15) * 8;
      float4 v = *(float4*)&lds_u[g * 4352 + ng * 136 + o8];
      *(float4*)&dst[(size_t)ng * 128 + o8] = v;
    }
  }
}

// K2: stats. 2048 blocks x 16 n, XCD-affine claimed. 16 gathers in flight.
__global__ __launch_bounds__(256, 4) void k_stats(const unsigned short* __restrict__ localB,
    const unsigned short* __restrict__ edgeB, const int* __restrict__ knn,
    float* __restrict__ partials, int* __restrict__ q) {
  __shared__ int knn_s[256];
  __shared__ float red[512];
  __shared__ int sbc[2];
  const int t = threadIdx.x;
  if (t == 0) { int b_, c_; claim_chunk(q + 4, 512, b_, c_); sbc[0] = b_; sbc[1] = c_; }
  red[t] = 0.f; red[t + 256] = 0.f;
  __syncthreads();
  const int b = sbc[0];
  const int n0 = sbc[1] << 4;
  knn_s[t] = knn[((size_t)b * N_ + n0) * K_ + t];
  __syncthreads();
  const int slot = t >> 4;
  const int co = t & 15;
  const unsigned short* lb = localB + (size_t)b * N_ * 128;
  const unsigned short* eb = edgeB + (size_t)b * N_ * 128;
  uint4 lu = *(const uint4*)&lb[(size_t)(n0 + slot) * 128 + co * 8];
  float l[8]; unpack8(lu, l);
  uint4 eu[16];
#pragma unroll
  for (int k = 0; k < 16; k++)
    eu[k] = *(const uint4*)&eb[(size_t)knn_s[slot * 16 + k] * 128 + co * 8];
  float se[8] = {0,0,0,0,0,0,0,0}, se2[8] = {0,0,0,0,0,0,0,0};
#pragma unroll
  for (int k = 0; k < 16; k++) {
    float e[8]; unpack8(eu[k], e);
#pragma unroll
    for (int j = 0; j < 8; j++) { se[j] += e[j]; se2[j] = fmaf(e[j], e[j], se2[j]); }
  }
  float lS[8], lQ[8], dS[8], dQ[8];
#pragma unroll
  for (int j = 0; j < 8; j++) {
    lS[j] = l[j];
    lQ[j] = l[j] * l[j];
    dS[j] = se[j] - 16.f * l[j];
    dQ[j] = fmaf(-2.f * l[j], se[j], se2[j]) + 16.f * lQ[j];
  }
#pragma unroll
  for (int off = 16; off <= 32; off <<= 1) {
#pragma unroll
    for (int j = 0; j < 8; j++) {
      lS[j] += __shfl_xor(lS[j], off);
      lQ[j] += __shfl_xor(lQ[j], off);
      dS[j] += __shfl_xor(dS[j], off);
      dQ[j] += __shfl_xor(dQ[j], off);
    }
  }
  if ((t & 48) == 0) {
    int ch = co * 8;
#pragma unroll
    for (int j = 0; j < 8; j++) {
      atomicAdd(&red[ch + j], lS[j]);
      atomicAdd(&red[128 + ch + j], dS[j]);
      atomicAdd(&red[256 + ch + j], lQ[j]);
      atomicAdd(&red[384 + ch + j], dQ[j]);
    }
  }
  __syncthreads();
  float* pb = partials + (size_t)blockIdx.x * 512;
  pb[t] = red[t];
  pb[t + 256] = red[t + 256];
}

// K3: reduce partials -> per-channel affine coefs y = a*x + b.
__global__ __launch_bounds__(256) void k_coef(const float* __restrict__ partials,
    const float* __restrict__ gamma, const float* __restrict__ beta,
    float* __restrict__ coef) {
  const int c = blockIdx.x;
  const int t = threadIdx.x;
  float s = 0.f, q = 0.f;
  for (int j = t; j < NBLK_STATS; j += 256) {
    s += partials[(size_t)j * 512 + c];
    q += partials[(size_t)j * 512 + 256 + c];
  }
#pragma unroll
  for (int off = 32; off > 0; off >>= 1) {
    s += __shfl_down(s, off);
    q += __shfl_down(q, off);
  }
  __shared__ float rs[4], rq[4];
  int w = t >> 6;
  if ((t & 63) == 0) { rs[w] = s; rq[w] = q; }
  __syncthreads();
  if (t == 0) {
    float S = rs[0] + rs[1] + rs[2] + rs[3];
    float Q = rq[0] + rq[1] + rq[2] + rq[3];
    float cnt = (c < 128) ? (float)(B_ * N_) : (float)(B_ * N_ * K_);
    float mean = S / cnt;
    float var = fmaxf(Q / cnt - mean * mean, 0.f);
    float a = gamma[c] * rsqrtf(var + 1e-5f);
    coef[c] = a;
    coef[256 + c] = beta[c] - mean * a;
  }
}

// K4: output. 1024 blocks x 32 n, XCD-affine claimed. 16-deep gathers,
// LDS transpose, NT float4 stores.
__global__ __launch_bounds__(256, 3) void k_out(const unsigned short* __restrict__ localB,
    const unsigned short* __restrict__ edgeB, const int* __restrict__ knn,
    const float* __restrict__ coef, float* __restrict__ out, int* __restrict__ q) {
  __shared__ float tile[256][36];
  __shared__ int knn_s[512];
  __shared__ int sbc[2];
  const int t = threadIdx.x;
  if (t == 0) { int b_, c_; claim_chunk(q + 8, 256, b_, c_); sbc[0] = b_; sbc[1] = c_; }
  __syncthreads();
  const int b = sbc[0];
  const int n0 = sbc[1] << 5;
  const int* kb = knn + ((size_t)b * N_ + n0) * K_;
  knn_s[t] = kb[t];
  knn_s[t + 256] = kb[t + 256];
  __syncthreads();
  const int slot = t >> 4;
  const int co = t & 15;
  float caL[8], cbL[8], caE[8], cbE[8];
  *(float4*)&caL[0] = *(const float4*)&coef[co * 8];
  *(float4*)&caL[4] = *(const float4*)&coef[co * 8 + 4];
  *(float4*)&caE[0] = *(const float4*)&coef[128 + co * 8];
  *(float4*)&caE[4] = *(const float4*)&coef[128 + co * 8 + 4];
  *(float4*)&cbL[0] = *(const float4*)&coef[256 + co * 8];
  *(float4*)&cbL[4] = *(const float4*)&coef[256 + co * 8 + 4];
  *(float4*)&cbE[0] = *(const float4*)&coef[384 + co * 8];
  *(float4*)&cbE[4] = *(const float4*)&coef[384 + co * 8 + 4];
  const unsigned short* lb = localB + (size_t)b * N_ * 128;
  const unsigned short* eb = edgeB + (size_t)b * N_ * 128;
#pragma unroll
  for (int h = 0; h < 2; h++) {
    int nl = slot + h * 16;
    uint4 lu = *(const uint4*)&lb[(size_t)(n0 + nl) * 128 + co * 8];
    float l[8]; unpack8(lu, l);
    float hc[8];
#pragma unroll
    for (int j = 0; j < 8; j++) hc[j] = fmaf(-l[j], caE[j], cbE[j]);
    uint4 eu[16];
#pragma unroll
    for (int k = 0; k < 16; k++)
      eu[k] = *(const uint4*)&eb[(size_t)knn_s[nl * 16 + k] * 128 + co * 8];
    float acc[8] = {0,0,0,0,0,0,0,0};
#pragma unroll
    for (int k = 0; k < 16; k++) {
      float e[8]; unpack8(eu[k], e);
#pragma unroll
      for (int j = 0; j < 8; j++)
        acc[j] += fmaxf(fmaf(e[j], caE[j], hc[j]), 0.f);
    }
#pragma unroll
    for (int j = 0; j < 8; j++) {
      tile[co * 8 + j][nl] = fmaxf(fmaf(l[j], caL[j], cbL[j]), 0.f);
      tile[128 + co * 8 + j][nl] = acc[j] * 0.0625f;
    }
  }
  __syncthreads();
  float* ob = out + (size_t)b * 256 * N_;
  const int cr = t >> 3;
  const int n4 = (t & 7) << 2;
#pragma unroll
  for (int p = 0; p < 8; p++) {
    int c = (p << 5) + cr;
    floatx4 v = *(floatx4*)&tile[c][n4];
    __builtin_nontemporal_store(v, (floatx4*)&ob[(size_t)c * N_ + n0 + n4]);
  }
}

extern "C" void kernel_launch(void* const* d_in, const int* in_sizes, int n_in,
                              void* d_out, int out_size, void* d_ws, size_t ws_size,
                              hipStream_t stream) {
  const float* feat  = (const float*)d_in[0];
  const int*   knn   = (const int*)d_in[1];
  const float* w1    = (const float*)d_in[2];
  const float* w2    = (const float*)d_in[3];
  const float* gamma = (const float*)d_in[4];
  const float* beta  = (const float*)d_in[5];
  if (ws_size < WS_BYTES) return;
  unsigned char* ws = (unsigned char*)d_ws;
  unsigned short* localB = (unsigned short*)(ws + OFF_LOCAL);
  unsigned short* edgeB  = (unsigned short*)(ws + OFF_EDGE);
  unsigned short* wbf1   = (unsigned short*)(ws + OFF_WBF1);
  unsigned short* wbf2   = (unsigned short*)(ws + OFF_WBF2);
  float* partials        = (float*)(ws + OFF_PART);
  float* coef            = (float*)(ws + OFF_COEF);
  int*   q               = (int*)(ws + OFF_Q);
  float* outp = (float*)d_out;

  hipLaunchKernelGGL(k_init, dim3(64), dim3(256), 0, stream, w1, w2, wbf1, wbf2, q);
  hipLaunchKernelGGL(k_gemm, dim3(1024), dim3(256), 0, stream, feat, wbf1, wbf2, localB, edgeB, q);
  hipLaunchKernelGGL(k_stats, dim3(2048), dim3(256), 0, stream, localB, edgeB, knn, partials, q);
  hipLaunchKernelGGL(k_coef, dim3(256), dim3(256), 0, stream, partials, gamma, beta, coef);
  hipLaunchKernelGGL(k_out, dim3(1024), dim3(256), 0, stream, localB, edgeB, knn, coef, outp, q);
}

// Round 8
// 152.439 us; speedup vs baseline: 1.9594x; 1.2500x over previous
//
#include <hip/hip_runtime.h>
#include <hip/hip_bf16.h>

#define B_ 4
#define C_ 128
#define N_ 8192
#define K_ 16
#define NBLK_STATS 2048

typedef __attribute__((ext_vector_type(8))) short short8;
typedef __attribute__((ext_vector_type(4))) float floatx4;
typedef __attribute__((ext_vector_type(2))) float floatx2;

static __device__ __forceinline__ unsigned short f2b(float x) {
  return __builtin_bit_cast(unsigned short, __float2bfloat16(x));
}
static __device__ __forceinline__ void unpack8(uint4 u, float* f) {
  const unsigned* w = (const unsigned*)&u;
#pragma unroll
  for (int i = 0; i < 4; i++) {
    f[2 * i]     = __builtin_bit_cast(float, w[i] << 16);
    f[2 * i + 1] = __builtin_bit_cast(float, w[i] & 0xffff0000u);
  }
}
// 8 fp8(e4m3, OCP on gfx950) -> 8 floats via HW cvt
static __device__ __forceinline__ void unpack8f8(uint2 u, float* f) {
  *(floatx2*)&f[0] = __builtin_amdgcn_cvt_pk_f32_fp8(u.x, false);
  *(floatx2*)&f[2] = __builtin_amdgcn_cvt_pk_f32_fp8(u.x, true);
  *(floatx2*)&f[4] = __builtin_amdgcn_cvt_pk_f32_fp8(u.y, false);
  *(floatx2*)&f[6] = __builtin_amdgcn_cvt_pk_f32_fp8(u.y, true);
}
static __device__ __forceinline__ unsigned pack4f8(float a, float b, float c, float d) {
  int v = __builtin_amdgcn_cvt_pk_fp8_f32(a, b, 0, false);
  v = __builtin_amdgcn_cvt_pk_fp8_f32(c, d, v, true);
  return (unsigned)v;
}

// workspace byte offsets
#define OFF_LOCAL 0ULL            // 8 MB bf16 (b,n,o)
#define OFF_EDGE  8388608ULL      // 4 MB fp8  (b,n,o)
#define OFF_WBF1  12582912ULL
#define OFF_WBF2  12615680ULL
#define OFF_PART  12648448ULL     // 2048*512 floats
#define OFF_COEF  16842752ULL
#define WS_BYTES  16844800ULL

// K0: cast W -> bf16.
__global__ __launch_bounds__(256) void k_prep(const float* __restrict__ w1,
    const float* __restrict__ w2, unsigned short* __restrict__ wbf1,
    unsigned short* __restrict__ wbf2) {
  int i = blockIdx.x * 256 + threadIdx.x;
  wbf1[i] = f2b(w1[i]);
  wbf2[i] = f2b(w2[i]);
}

// Static XCD-affine swizzle (R5-best): batch b on blockIdx%8 in {2b,2b+1}.
static __device__ __forceinline__ void swz(int bid, int& b, int& chunk) {
  b = (bid & 7) >> 1;
  chunk = ((bid >> 3) << 1) | (bid & 1);
}

// K1: MFMA dual-GEMM. local -> bf16 (256 B rows), edge -> fp8 e4m3 (128 B rows).
// 1024 blocks x 32 n. Waves 0-1: W1/local, waves 2-3: W2/edge.
__global__ __launch_bounds__(256, 4) void k_gemm(const float* __restrict__ feat,
    const unsigned short* __restrict__ wbf1, const unsigned short* __restrict__ wbf2,
    unsigned short* __restrict__ localB, unsigned char* __restrict__ edgeF,
    int dummy) {
  __shared__ __align__(16) unsigned char lds_raw[13312];
  unsigned short* stage = (unsigned short*)lds_raw;   // [128 c][36 n] bf16
  unsigned short* ldsL  = (unsigned short*)lds_raw;   // [32 n][136] bf16 (after sync)
  unsigned char*  ldsE  = lds_raw + 8704;             // [32 n][144 B] fp8
  const int t = threadIdx.x;
  int b, chunk; swz(blockIdx.x, b, chunk);
  const int n0 = chunk << 5;
  const float* fb = feat + (size_t)b * C_ * N_;
#pragma unroll
  for (int i = 0; i < 4; i++) {
    int c = i * 32 + (t >> 3);
    int n4 = (t & 7) << 2;
    floatx4 f = __builtin_nontemporal_load((const floatx4*)&fb[(size_t)c * N_ + n0 + n4]);
    ushort4 u = make_ushort4(f2b(f[0]), f2b(f[1]), f2b(f[2]), f2b(f[3]));
    *(ushort4*)&stage[c * 36 + n4] = u;
  }
  __syncthreads();
  const int lane = t & 63, wv = t >> 6, l15 = lane & 15, qd = lane >> 4;
  const int gw = wv >> 1, nt = wv & 1;
  short8 bfrag[4];
#pragma unroll
  for (int ks = 0; ks < 4; ks++)
#pragma unroll
    for (int j = 0; j < 8; j++)
      bfrag[ks][j] = (short)stage[(ks * 32 + qd * 8 + j) * 36 + nt * 16 + l15];
  __syncthreads();   // staging consumed; LDS reused for output tiles
  const unsigned short* Wg = gw ? wbf2 : wbf1;
  floatx4 acc[8];
#pragma unroll
  for (int mt = 0; mt < 8; mt++) acc[mt] = (floatx4){0.f, 0.f, 0.f, 0.f};
#pragma unroll
  for (int ks = 0; ks < 4; ks++) {
    short8 af[8];
#pragma unroll
    for (int mt = 0; mt < 8; mt++)
      af[mt] = *(const short8*)(Wg + (size_t)(mt * 16 + l15) * 128 + ks * 32 + qd * 8);
#pragma unroll
    for (int mt = 0; mt < 8; mt++)
      acc[mt] = __builtin_amdgcn_mfma_f32_16x16x32_bf16(af[mt], bfrag[ks], acc[mt], 0, 0, 0);
  }
  // D[o = mt*16+qd*4+r][n = nt*16+l15]
  if (gw == 0) {
#pragma unroll
    for (int mt = 0; mt < 8; mt++) {
      ushort4 u = make_ushort4(f2b(acc[mt][0]), f2b(acc[mt][1]), f2b(acc[mt][2]), f2b(acc[mt][3]));
      *(ushort4*)&ldsL[(nt * 16 + l15) * 136 + mt * 16 + qd * 4] = u;
    }
  } else {
#pragma unroll
    for (int mt = 0; mt < 8; mt++) {
      unsigned u = pack4f8(acc[mt][0], acc[mt][1], acc[mt][2], acc[mt][3]);
      *(unsigned*)&ldsE[(nt * 16 + l15) * 144 + mt * 16 + qd * 4] = u;
    }
  }
  __syncthreads();
  {
    unsigned short* dst = localB + ((size_t)b * N_ + n0) * 128;
#pragma unroll
    for (int i = 0; i < 2; i++) {
      int ng = i * 16 + (t >> 4);
      int o8 = (t & 15) * 8;
      float4 v = *(float4*)&ldsL[ng * 136 + o8];
      *(float4*)&dst[(size_t)ng * 128 + o8] = v;
    }
  }
  {
    unsigned char* dst = edgeF + ((size_t)b * N_ + n0) * 128;
    int ng = t >> 3;
    int o16 = (t & 7) * 16;
    uint4 v = *(uint4*)&ldsE[ng * 144 + o16];
    *(uint4*)&dst[(size_t)ng * 128 + o16] = v;
  }
}

// K2: stats. 2048 blocks x 16 n. fp8 edge gathers (2 lines/row), 16 in flight.
__global__ __launch_bounds__(256, 4) void k_stats(const unsigned short* __restrict__ localB,
    const unsigned char* __restrict__ edgeF, const int* __restrict__ knn,
    float* __restrict__ partials) {
  __shared__ int knn_s[256];
  __shared__ float red[512];
  const int t = threadIdx.x;
  int b, chunk; swz(blockIdx.x, b, chunk);
  const int n0 = chunk << 4;
  red[t] = 0.f; red[t + 256] = 0.f;
  knn_s[t] = knn[((size_t)b * N_ + n0) * K_ + t];
  __syncthreads();
  const int slot = t >> 4;
  const int co = t & 15;
  const unsigned short* lb = localB + (size_t)b * N_ * 128;
  const unsigned char* eb = edgeF + (size_t)b * N_ * 128;
  uint4 lu = *(const uint4*)&lb[(size_t)(n0 + slot) * 128 + co * 8];
  float l[8]; unpack8(lu, l);
  uint2 eu[16];
#pragma unroll
  for (int k = 0; k < 16; k++)
    eu[k] = *(const uint2*)&eb[(size_t)knn_s[slot * 16 + k] * 128 + co * 8];
  float se[8] = {0,0,0,0,0,0,0,0}, se2[8] = {0,0,0,0,0,0,0,0};
#pragma unroll
  for (int k = 0; k < 16; k++) {
    float e[8]; unpack8f8(eu[k], e);
#pragma unroll
    for (int j = 0; j < 8; j++) { se[j] += e[j]; se2[j] = fmaf(e[j], e[j], se2[j]); }
  }
  float lS[8], lQ[8], dS[8], dQ[8];
#pragma unroll
  for (int j = 0; j < 8; j++) {
    lS[j] = l[j];
    lQ[j] = l[j] * l[j];
    dS[j] = se[j] - 16.f * l[j];
    dQ[j] = fmaf(-2.f * l[j], se[j], se2[j]) + 16.f * lQ[j];
  }
#pragma unroll
  for (int off = 16; off <= 32; off <<= 1) {
#pragma unroll
    for (int j = 0; j < 8; j++) {
      lS[j] += __shfl_xor(lS[j], off);
      lQ[j] += __shfl_xor(lQ[j], off);
      dS[j] += __shfl_xor(dS[j], off);
      dQ[j] += __shfl_xor(dQ[j], off);
    }
  }
  if ((t & 48) == 0) {
    int ch = co * 8;
#pragma unroll
    for (int j = 0; j < 8; j++) {
      atomicAdd(&red[ch + j], lS[j]);
      atomicAdd(&red[128 + ch + j], dS[j]);
      atomicAdd(&red[256 + ch + j], lQ[j]);
      atomicAdd(&red[384 + ch + j], dQ[j]);
    }
  }
  __syncthreads();
  float* pb = partials + (size_t)blockIdx.x * 512;
  pb[t] = red[t];
  pb[t + 256] = red[t + 256];
}

// K3: reduce partials -> per-channel affine coefs y = a*x + b.
__global__ __launch_bounds__(256) void k_coef(const float* __restrict__ partials,
    const float* __restrict__ gamma, const float* __restrict__ beta,
    float* __restrict__ coef) {
  const int c = blockIdx.x;
  const int t = threadIdx.x;
  float s = 0.f, q = 0.f;
  for (int j = t; j < NBLK_STATS; j += 256) {
    s += partials[(size_t)j * 512 + c];
    q += partials[(size_t)j * 512 + 256 + c];
  }
#pragma unroll
  for (int off = 32; off > 0; off >>= 1) {
    s += __shfl_down(s, off);
    q += __shfl_down(q, off);
  }
  __shared__ float rs[4], rq[4];
  int w = t >> 6;
  if ((t & 63) == 0) { rs[w] = s; rq[w] = q; }
  __syncthreads();
  if (t == 0) {
    float S = rs[0] + rs[1] + rs[2] + rs[3];
    float Q = rq[0] + rq[1] + rq[2] + rq[3];
    float cnt = (c < 128) ? (float)(B_ * N_) : (float)(B_ * N_ * K_);
    float mean = S / cnt;
    float var = fmaxf(Q / cnt - mean * mean, 0.f);
    float a = gamma[c] * rsqrtf(var + 1e-5f);
    coef[c] = a;
    coef[256 + c] = beta[c] - mean * a;
  }
}

// K4: output. 1024 blocks x 32 n. fp8 gathers, LDS transpose, NT float4 stores.
__global__ __launch_bounds__(256, 3) void k_out(const unsigned short* __restrict__ localB,
    const unsigned char* __restrict__ edgeF, const int* __restrict__ knn,
    const float* __restrict__ coef, float* __restrict__ out) {
  __shared__ float tile[256][36];
  __shared__ int knn_s[512];
  const int t = threadIdx.x;
  int b, chunk; swz(blockIdx.x, b, chunk);
  const int n0 = chunk << 5;
  const int* kb = knn + ((size_t)b * N_ + n0) * K_;
  knn_s[t] = kb[t];
  knn_s[t + 256] = kb[t + 256];
  __syncthreads();
  const int slot = t >> 4;
  const int co = t & 15;
  float caL[8], cbL[8], caE[8], cbE[8];
  *(float4*)&caL[0] = *(const float4*)&coef[co * 8];
  *(float4*)&caL[4] = *(const float4*)&coef[co * 8 + 4];
  *(float4*)&caE[0] = *(const float4*)&coef[128 + co * 8];
  *(float4*)&caE[4] = *(const float4*)&coef[128 + co * 8 + 4];
  *(float4*)&cbL[0] = *(const float4*)&coef[256 + co * 8];
  *(float4*)&cbL[4] = *(const float4*)&coef[256 + co * 8 + 4];
  *(float4*)&cbE[0] = *(const float4*)&coef[384 + co * 8];
  *(float4*)&cbE[4] = *(const float4*)&coef[384 + co * 8 + 4];
  const unsigned short* lb = localB + (size_t)b * N_ * 128;
  const unsigned char* eb = edgeF + (size_t)b * N_ * 128;
#pragma unroll
  for (int h = 0; h < 2; h++) {
    int nl = slot + h * 16;
    uint4 lu = *(const uint4*)&lb[(size_t)(n0 + nl) * 128 + co * 8];
    float l[8]; unpack8(lu, l);
    float hc[8];
#pragma unroll
    for (int j = 0; j < 8; j++) hc[j] = fmaf(-l[j], caE[j], cbE[j]);
    uint2 eu[16];
#pragma unroll
    for (int k = 0; k < 16; k++)
      eu[k] = *(const uint2*)&eb[(size_t)knn_s[nl * 16 + k] * 128 + co * 8];
    float acc[8] = {0,0,0,0,0,0,0,0};
#pragma unroll
    for (int k = 0; k < 16; k++) {
      float e[8]; unpack8f8(eu[k], e);
#pragma unroll
      for (int j = 0; j < 8; j++)
        acc[j] += fmaxf(fmaf(e[j], caE[j], hc[j]), 0.f);
    }
#pragma unroll
    for (int j = 0; j < 8; j++) {
      tile[co * 8 + j][nl] = fmaxf(fmaf(l[j], caL[j], cbL[j]), 0.f);
      tile[128 + co * 8 + j][nl] = acc[j] * 0.0625f;
    }
  }
  __syncthreads();
  float* ob = out + (size_t)b * 256 * N_;
  const int cr = t >> 3;
  const int n4 = (t & 7) << 2;
#pragma unroll
  for (int p = 0; p < 8; p++) {
    int c = (p << 5) + cr;
    floatx4 v = *(floatx4*)&tile[c][n4];
    __builtin_nontemporal_store(v, (floatx4*)&ob[(size_t)c * N_ + n0 + n4]);
  }
}

extern "C" void kernel_launch(void* const* d_in, const int* in_sizes, int n_in,
                              void* d_out, int out_size, void* d_ws, size_t ws_size,
                              hipStream_t stream) {
  const float* feat  = (const float*)d_in[0];
  const int*   knn   = (const int*)d_in[1];
  const float* w1    = (const float*)d_in[2];
  const float* w2    = (const float*)d_in[3];
  const float* gamma = (const float*)d_in[4];
  const float* beta  = (const float*)d_in[5];
  if (ws_size < WS_BYTES) return;
  unsigned char* ws = (unsigned char*)d_ws;
  unsigned short* localB = (unsigned short*)(ws + OFF_LOCAL);
  unsigned char*  edgeF  = (unsigned char*)(ws + OFF_EDGE);
  unsigned short* wbf1   = (unsigned short*)(ws + OFF_WBF1);
  unsigned short* wbf2   = (unsigned short*)(ws + OFF_WBF2);
  float* partials        = (float*)(ws + OFF_PART);
  float* coef            = (float*)(ws + OFF_COEF);
  float* outp = (float*)d_out;

  hipLaunchKernelGGL(k_prep, dim3(64), dim3(256), 0, stream, w1, w2, wbf1, wbf2);
  hipLaunchKernelGGL(k_gemm, dim3(1024), dim3(256), 0, stream, feat, wbf1, wbf2, localB, edgeF, 0);
  hipLaunchKernelGGL(k_stats, dim3(2048), dim3(256), 0, stream, localB, edgeF, knn, partials);
  hipLaunchKernelGGL(k_coef, dim3(256), dim3(256), 0, stream, partials, gamma, beta, coef);
  hipLaunchKernelGGL(k_out, dim3(1024), dim3(256), 0, stream, localB, edgeF, knn, coef, outp);
}